// Round 12
// baseline (108.076 us; speedup 1.0000x reference)
//
#include <hip/hip_runtime.h>
#include <hip/hip_bf16.h>

#define N_NODES 100000
#define DEG 16
#define D 128

typedef __bf16 bf16x8 __attribute__((ext_vector_type(8)));
typedef float f32x4 __attribute__((ext_vector_type(4)));
typedef float f32x4e __attribute__((ext_vector_type(4)));
typedef unsigned u32x4 __attribute__((ext_vector_type(4)));

__device__ __forceinline__ unsigned pk2(float a, float b) {
  union { __bf16 h[2]; unsigned u; } x;
  x.h[0] = (__bf16)a; x.h[1] = (__bf16)b;
  return x.u;
}

// swizzled element index into a [128][128] ushort tile (XOR bits 3..5 of k with row bits 0..2)
__device__ __forceinline__ int swz(int row, int k) {
  return (row << 7) + (k ^ ((row & 7) << 3));
}

// Kernel 0: W [k][n] f32 -> Wt bf16 transposed [n][k], swizzled (64 blocks, 1 elem/thread)
__global__ void k_convW(const float* __restrict__ W, ushort* __restrict__ Wt) {
  int pos = (blockIdx.x << 8) + threadIdx.x;   // 0..16383
  int k = pos >> 7, n = pos & 127;
  union { __bf16 h; ushort u; } c;
  c.h = (__bf16)W[pos];
  Wt[swz(n, k)] = c.u;
}

// Kernel 1: Xb = bf16(X), logical row-major. Pure stream: 8 elems/thread.
__global__ __launch_bounds__(256) void k_cvtX(const float* __restrict__ X,
                                              ushort* __restrict__ Xb) {
  int t = (blockIdx.x << 8) + threadIdx.x;     // 1.6M threads exactly
  const float* p = X + (t << 3);
  f32x4e a = __builtin_nontemporal_load((const f32x4e*)p);
  f32x4e b = __builtin_nontemporal_load((const f32x4e*)(p + 4));
  u32x4 v;
  v.x = pk2(a[0], a[1]); v.y = pk2(a[2], a[3]);
  v.z = pk2(b[0], b[1]); v.w = pk2(b[2], b[3]);
  __builtin_nontemporal_store(v, (u32x4*)(Xb + (t << 3)));
}

// Kernel 2 (fused): out[i] = (sum_e Xb[ci[e]]) @ W.
// One wave per 16 output rows. Lane (lhi=lane>>4, llo=lane&15) accumulates
// S[llo][t*32+lhi*8 .. +8] (t=0..3) over the row's 16 edges; 64-byte-segment
// coalesced gathers. Then S -> bf16 A-frags, 32 MFMA vs L1-resident Wt,
// D layout col=llo,row=lhi*4+r -> coalesced 64B scalar stores.
__global__ __launch_bounds__(256) void k_fused(const ushort* __restrict__ Xb,
                                               const ushort* __restrict__ Wt,
                                               const int* __restrict__ ci,
                                               float* __restrict__ out) {
  const int wave = threadIdx.x >> 6;
  const int lane = threadIdx.x & 63;
  const int lhi = lane >> 4;
  const int llo = lane & 15;
  const int row0 = (blockIdx.x << 6) + (wave << 4);
  if (row0 >= N_NODES) return;                 // N_NODES % 16 == 0: clean wave tail

  // 256 indices for rows row0..row0+15: one uint4 per lane
  u32x4 iv = __builtin_nontemporal_load((const u32x4*)(ci + (row0 << 4)) + lane);

  float s0[8], s1[8], s2[8], s3[8];
#pragma unroll
  for (int i = 0; i < 8; ++i) { s0[i] = 0.f; s1[i] = 0.f; s2[i] = 0.f; s3[i] = 0.f; }

  const ushort* tb = Xb + (lhi << 3);
#pragma unroll
  for (int e = 0; e < DEG; ++e) {
    // flat index position llo*16+e lives in lane llo*4+(e>>2), component e&3
    int idx = __shfl((int)iv[e & 3], (llo << 2) + (e >> 2));
    const ushort* rp = tb + idx * D;
    u32x4 q0 = *(const u32x4*)(rp);
    u32x4 q1 = *(const u32x4*)(rp + 32);
    u32x4 q2 = *(const u32x4*)(rp + 64);
    u32x4 q3 = *(const u32x4*)(rp + 96);
#pragma unroll
    for (int w = 0; w < 4; ++w) {
      s0[2 * w]     += __uint_as_float(q0[w] << 16);
      s0[2 * w + 1] += __uint_as_float(q0[w] & 0xffff0000u);
      s1[2 * w]     += __uint_as_float(q1[w] << 16);
      s1[2 * w + 1] += __uint_as_float(q1[w] & 0xffff0000u);
      s2[2 * w]     += __uint_as_float(q2[w] << 16);
      s2[2 * w + 1] += __uint_as_float(q2[w] & 0xffff0000u);
      s3[2 * w]     += __uint_as_float(q3[w] << 16);
      s3[2 * w + 1] += __uint_as_float(q3[w] & 0xffff0000u);
    }
  }

  // S -> bf16 A-fragments (af[t] holds k = t*32+lhi*8 .. +8 of row llo)
  bf16x8 af[4];
  {
    union { unsigned u[4]; bf16x8 v; } c0, c1, c2, c3;
#pragma unroll
    for (int w = 0; w < 4; ++w) {
      c0.u[w] = pk2(s0[2 * w], s0[2 * w + 1]);
      c1.u[w] = pk2(s1[2 * w], s1[2 * w + 1]);
      c2.u[w] = pk2(s2[2 * w], s2[2 * w + 1]);
      c3.u[w] = pk2(s3[2 * w], s3[2 * w + 1]);
    }
    af[0] = c0.v; af[1] = c1.v; af[2] = c2.v; af[3] = c3.v;
  }

  f32x4 acc[8];
#pragma unroll
  for (int n = 0; n < 8; ++n) acc[n] = (f32x4){0.f, 0.f, 0.f, 0.f};

#pragma unroll
  for (int t = 0; t < 4; ++t) {
    const int k0 = (t << 5) + (lhi << 3);
#pragma unroll
    for (int n = 0; n < 8; ++n) {
      bf16x8 b = *(const bf16x8*)(Wt + swz((n << 4) + llo, k0));
      acc[n] = __builtin_amdgcn_mfma_f32_16x16x32_bf16(af[t], b, acc[n], 0, 0, 0);
    }
  }

  // store: lane holds out[row0+lhi*4+r][n*16+llo]
#pragma unroll
  for (int r = 0; r < 4; ++r) {
    float* op = out + (row0 + (lhi << 2) + r) * D + llo;
#pragma unroll
    for (int n = 0; n < 8; ++n)
      __builtin_nontemporal_store(acc[n][r], op + (n << 4));
  }
}

extern "C" void kernel_launch(void* const* d_in, const int* in_sizes, int n_in,
                              void* d_out, int out_size, void* d_ws, size_t ws_size,
                              hipStream_t stream) {
  const float* X = (const float*)d_in[0];
  const float* W = (const float*)d_in[1];
  const int* ci = (const int*)d_in[3];

  ushort* Wt = (ushort*)d_ws;                 // 32 KB
  ushort* Xb = (ushort*)d_ws + 128 * 128;     // 25.6 MB bf16 X (logical layout)
  float* out = (float*)d_out;

  k_convW<<<64, 256, 0, stream>>>(W, Wt);
  k_cvtX<<<(N_NODES * D / 8) / 256, 256, 0, stream>>>(X, Xb);
  k_fused<<<(N_NODES + 63) / 64, 256, 0, stream>>>(Xb, Wt, ci, out);
}

// Round 13
// 82.799 us; speedup vs baseline: 1.3053x; 1.3053x over previous
//
#include <hip/hip_runtime.h>
#include <hip/hip_bf16.h>

#define N_NODES 100000
#define DEG 16
#define D 128

typedef __bf16 bf16x8 __attribute__((ext_vector_type(8)));
typedef float f32x4 __attribute__((ext_vector_type(4)));

__device__ __forceinline__ unsigned pk2(float a, float b) {
  union { __bf16 h[2]; unsigned u; } x;
  x.h[0] = (__bf16)a; x.h[1] = (__bf16)b;
  return x.u;
}

// swizzled element index into a [128][128] ushort LDS tile (XOR bits 3..5 of k with row bits 0..2)
__device__ __forceinline__ int swz(int row, int k) {
  return (row << 7) + (k ^ ((row & 7) << 3));
}

// Kernel 0: W [k][n] f32 -> Wt bf16 transposed [n][k], swizzled (64 blocks, 1 elem/thread)
__global__ void k_convW(const float* __restrict__ W, ushort* __restrict__ Wt) {
  int pos = (blockIdx.x << 8) + threadIdx.x;   // 0..16383
  int k = pos >> 7, n = pos & 127;
  union { __bf16 h; ushort u; } c;
  c.h = (__bf16)W[pos];
  Wt[swz(n, k)] = c.u;
}

// Kernel 1: Xp = bf16(X @ W), rows stored in permuted col order: pos p=llo*8+n <-> col n*16+llo.
// 128-row tile per block, 4 waves x 32 rows (m=0,1). A-loads issued FIRST so their HBM
// latency hides under the 32 KB Ws staging copy; one barrier; MFMA; packed uint4 epilogue.
__global__ __launch_bounds__(256, 2) void k_gemm(const float* __restrict__ X,
                                                 const ushort* __restrict__ Wt,
                                                 ushort* __restrict__ Xp) {
  __shared__ __align__(16) ushort Ws[128 * 128];
  const int tid = threadIdx.x;
  const int row0 = blockIdx.x << 7;
  const int wave = tid >> 6;
  const int lane = tid & 63;
  const int lhi = lane >> 4;           // 0..3
  const int llo = lane & 15;

  // 1) issue all 16 A-fragment loads first: lane owns row (per m), k-slice lhi*8 (per t)
  float4 t0[2][4], t1[2][4];
#pragma unroll
  for (int m = 0; m < 2; ++m) {
    int row = row0 + (wave << 5) + (m << 4) + llo;
    const float* rp = X + row * D + (lhi << 3);
    bool ok = row < N_NODES;
#pragma unroll
    for (int t = 0; t < 4; ++t) {
      t0[m][t] = ok ? *(const float4*)(rp + (t << 5)) : make_float4(0.f, 0.f, 0.f, 0.f);
      t1[m][t] = ok ? *(const float4*)(rp + (t << 5) + 4) : make_float4(0.f, 0.f, 0.f, 0.f);
    }
  }

  // 2) stage pre-swizzled Wt (32 KB linear copy) while A loads are in flight
  {
    const uint4* src = (const uint4*)Wt;
    uint4* dst = (uint4*)Ws;
#pragma unroll
    for (int j = 0; j < 8; ++j) dst[(j << 8) + tid] = src[(j << 8) + tid];
  }

  // 3) convert A to bf16 (first use of the A loads -> waits here, after staging issued)
  bf16x8 af[2][4];
#pragma unroll
  for (int m = 0; m < 2; ++m)
#pragma unroll
    for (int t = 0; t < 4; ++t) {
      bf16x8 v;
      v[0] = (__bf16)t0[m][t].x; v[1] = (__bf16)t0[m][t].y;
      v[2] = (__bf16)t0[m][t].z; v[3] = (__bf16)t0[m][t].w;
      v[4] = (__bf16)t1[m][t].x; v[5] = (__bf16)t1[m][t].y;
      v[6] = (__bf16)t1[m][t].z; v[7] = (__bf16)t1[m][t].w;
      af[m][t] = v;
    }
  __syncthreads();

  f32x4 acc[2][8];
#pragma unroll
  for (int m = 0; m < 2; ++m)
#pragma unroll
    for (int n = 0; n < 8; ++n)
      acc[m][n] = (f32x4){0.f, 0.f, 0.f, 0.f};

#pragma unroll
  for (int t = 0; t < 4; ++t) {
    const int k0 = (t << 5) + (lhi << 3);
    bf16x8 b[8];
#pragma unroll
    for (int n = 0; n < 8; ++n)
      b[n] = *(const bf16x8*)(Ws + swz((n << 4) + llo, k0));
#pragma unroll
    for (int m = 0; m < 2; ++m)
#pragma unroll
      for (int n = 0; n < 8; ++n)
        acc[m][n] = __builtin_amdgcn_mfma_f32_16x16x32_bf16(af[m][t], b[n], acc[m][n], 0, 0, 0);
  }

  // epilogue: C/D layout col=llo, row=lhi*4+r. Pack 8 cols (n=0..7) -> uint4 per (m,r).
#pragma unroll
  for (int m = 0; m < 2; ++m) {
#pragma unroll
    for (int r = 0; r < 4; ++r) {
      int row = row0 + (wave << 5) + (m << 4) + (lhi << 2) + r;
      if (row < N_NODES) {
        uint4 v;
        v.x = pk2(acc[m][0][r], acc[m][1][r]);
        v.y = pk2(acc[m][2][r], acc[m][3][r]);
        v.z = pk2(acc[m][4][r], acc[m][5][r]);
        v.w = pk2(acc[m][6][r], acc[m][7][r]);
        *(uint4*)(Xp + row * D + (llo << 3)) = v;
      }
    }
  }
}

// Kernel 2: out[i] = sum_{e} Xp[ci[e]]  (one wave per row; Xp rows are col-permuted)
// Quarter-wave scheme: group g = lane>>4 handles edges 4g..4g+3; lane j = lane&15
// loads 16 B (positions j*8..j*8+8 = logical cols {n*16+j}). Cross-group reduce
// via shfl_xor(16,32); group-g store covers contiguous cols 32g..32g+31.
__global__ __launch_bounds__(256) void k_spmm(const ushort* __restrict__ Xp,
                                              const int* __restrict__ ci,
                                              float* __restrict__ out) {
  const int wave = threadIdx.x >> 6;
  const int lane = threadIdx.x & 63;
  const int row = (blockIdx.x << 2) + wave;
  if (row >= N_NODES) return;
  const int g = lane >> 4;
  const int j = lane & 15;

  int idx = 0;
  if (lane < DEG) idx = __builtin_nontemporal_load(ci + row * DEG + lane);

  uint4 v[4];
#pragma unroll
  for (int e = 0; e < 4; ++e) {
    int col = __shfl(idx, (g << 2) + e);
    v[e] = *(const uint4*)(Xp + col * D + (j << 3));
  }

  float acc[8];
#pragma unroll
  for (int n = 0; n < 8; ++n) acc[n] = 0.f;
#pragma unroll
  for (int e = 0; e < 4; ++e) {
    acc[0] += __uint_as_float(v[e].x << 16);
    acc[1] += __uint_as_float(v[e].x & 0xffff0000u);
    acc[2] += __uint_as_float(v[e].y << 16);
    acc[3] += __uint_as_float(v[e].y & 0xffff0000u);
    acc[4] += __uint_as_float(v[e].z << 16);
    acc[5] += __uint_as_float(v[e].z & 0xffff0000u);
    acc[6] += __uint_as_float(v[e].w << 16);
    acc[7] += __uint_as_float(v[e].w & 0xffff0000u);
  }

#pragma unroll
  for (int n = 0; n < 8; ++n) {
    acc[n] += __shfl_xor(acc[n], 16);
    acc[n] += __shfl_xor(acc[n], 32);
  }

  // lane (g,j): acc[n] holds col n*16+j; store acc[2g]->col 32g+j, acc[2g+1]->col 32g+16+j
  float* op = out + row * D + (g << 5) + j;
  __builtin_nontemporal_store(acc[(g << 1)], op);
  __builtin_nontemporal_store(acc[(g << 1) + 1], op + 16);
}

extern "C" void kernel_launch(void* const* d_in, const int* in_sizes, int n_in,
                              void* d_out, int out_size, void* d_ws, size_t ws_size,
                              hipStream_t stream) {
  const float* X = (const float*)d_in[0];
  const float* W = (const float*)d_in[1];
  const int* ci = (const int*)d_in[3];

  ushort* Wt = (ushort*)d_ws;                 // 32 KB
  ushort* Xp = (ushort*)d_ws + 128 * 128;     // 25.6 MB bf16 X' (permuted rows)
  float* out = (float*)d_out;

  k_convW<<<64, 256, 0, stream>>>(W, Wt);
  k_gemm<<<(N_NODES + 127) / 128, 256, 0, stream>>>(X, Wt, Xp);
  k_spmm<<<N_NODES / 4, 256, 0, stream>>>(Xp, ci, out);
}